// Round 6
// baseline (219.652 us; speedup 1.0000x reference)
//
#include <hip/hip_runtime.h>

// PDELoss fused, wave-autonomous, whole-strip-resident version.
// Each 64-lane wave owns one (image, 8-row strip); thread = 4 columns.
// R6 core idea: pay memory latency ONCE per wave. Prologue issues ALL strip
// loads back-to-back (12 pred float4 rows + 4 rhs rows; rhs rows 4..7 issued
// mid-blob with ~4 rows of compute cover), then a fully-unrolled 10-row
// register blob: dual stencil SL=sum(kl*p), SD=sum(kd*p) with kl/kd held in
// SGPRs (readfirstlane; GS = s*SL + (s/r)*SD), horizontal [1,2,1] via shfl,
// vertical [1,2,1]/16 via SSA gh rolls, MSE -> wave reduce -> per-block
// partial -> tiny reduce kernel.
//
// R1-R5 history: grid fill (null), launch_bounds cap -> spill (reverted),
// atomic-storm removal (65->54us), 2-row unroll ILP (54->50us). Counters
// closed only on: ~3000cy exposed latency PER BODY, ~2.7 waves/SIMD ->
// VALUBusy 24%, occ 33%. Loads were consumed same-body => ~5 latency
// exposures per wave. R6 makes it ONE exposure: MLP instead of TLP.
// c4[9] (36 VGPR) dropped for SGPR kl/kd + dual stencil (2x fma, free at
// 24% VALU) to fund p[12]+rhs residency. No launch_bounds waves arg (R1).

__global__ __launch_bounds__(256)
void pde_loss_kernel(const float* __restrict__ pred,   // [B,256,256]
                     const float* __restrict__ rhs,    // [B,254,254]
                     const float* __restrict__ KL,     // [B,3,3]
                     const float* __restrict__ KD,     // [B,3,3]
                     const float* __restrict__ RR,     // [B,256,256] (col-only)
                     const float* __restrict__ ZZ,     // [B,256,256] (row-only)
                     float* __restrict__ partials)     // [gridDim.x]
{
    constexpr int H = 256, W = 256, OH = 254, OW = 254, SR = 8;
    const int tid = threadIdx.x;
    const int l   = tid & 63;          // lane
    const int wv  = tid >> 6;          // wave in block (0..3)
    const int b   = blockIdx.x >> 3;   // image
    const int strip = (blockIdx.x & 7) * 4 + wv;   // 32 strips of 8 rows
    const int o0 = strip * SR;
    const int o1 = (o0 + SR < OH) ? (o0 + SR) : OH;   // last strip: 6 rows

    const size_t ib = (size_t)b * H * W;
    const float* predb = pred + ib;
    const float* rhsb  = rhs + (size_t)b * OH * OW;
    const int c0 = 4 * l;

    // ---------- issue the whole strip's pred loads up front (MLP) ----------
    // pred rows o0-1 .. o0+10 (12 rows); out-of-range rows stay zero.
    float4 p[12];
#pragma unroll
    for (int j = 0; j < 12; ++j) {
        const int row = o0 - 1 + j;
        p[j] = make_float4(0.f, 0.f, 0.f, 0.f);
        if ((unsigned)row < (unsigned)H)
            p[j] = *(const float4*)(predb + (size_t)row * W + c0);
    }
    // rhs rows 0..3 now; rows 4..7 issued inside the blob (4 rows of cover).
    float2 r0[8], r1[8];
#pragma unroll
    for (int j = 0; j < 8; ++j) { r0[j] = make_float2(0.f, 0.f); r1[j] = make_float2(0.f, 0.f); }
#pragma unroll
    for (int j = 0; j < 4; ++j) {           // o0+j < o1 always (o1 >= o0+6)
        const float* rr = rhsb + (size_t)(o0 + j) * OW + c0;
        r0[j] = *(const float2*)rr;
        if (c0 + 2 < OW) r1[j] = *(const float2*)(rr + 2);
    }

    // ---------- wave-uniform scalars: kl/kd pinned to SGPRs ----------
    const float hr  = RR[ib + W + 2] - RR[ib + W + 1];
    const float hz  = ZZ[ib + 2 * W + 1] - ZZ[ib + W + 1];
    const float hr2 = hr * hr, hz2 = hz * hz;
    const float s   = -2.0f * (hr2 + hz2) / (hr2 * hz2);
    float kl[9], kd[9];
#pragma unroll
    for (int t = 0; t < 9; ++t) {
        kl[t] = __int_as_float(__builtin_amdgcn_readfirstlane(__float_as_int(KL[b * 9 + t])));
        kd[t] = __int_as_float(__builtin_amdgcn_readfirstlane(__float_as_int(KD[b * 9 + t])));
    }

    // per-column combine factors: GS = s*SL + (s/r)*SD; lane63 z/w (cols
    // 254/255) zeroed via the s4/sir4 fold (kills gs AND lane0's wrap halo).
    const float mzw = (l == 63) ? 0.f : 1.f;
    const float m23 = (c0 + 2 < OW) ? 1.f : 0.f;  // emit cols c0+2,c0+3 valid
    const float m0  = (l > 0) ? 1.f : 0.f;        // left-halo validity
    float4 s4, sir4;
    {
        float4 invr;
        invr.x = 1.0f / RR[ib + W + (c0 + 1)];
        invr.y = 1.0f / RR[ib + W + (c0 + 2)];
        invr.z = 1.0f / RR[ib + W + (c0 + 3)];
        invr.w = 1.0f / RR[ib + W + ((c0 + 4 < W) ? (c0 + 4) : (W - 1))];
        s4.x = s; s4.y = s; s4.z = s * mzw; s4.w = s * mzw;
        sir4.x = s4.x * invr.x; sir4.y = s4.y * invr.y;
        sir4.z = s4.z * invr.z; sir4.w = s4.w * invr.w;
    }

    // dual-stencil row accumulate: SV += P (*) K[k0..k2] with right-halo nx,ny
#define SROW(SV, P, nx, ny, k0, k1, k2, KC)                                   \
    SV.x = fmaf(P.x, KC[k0], fmaf(P.y, KC[k1], fmaf(P.z, KC[k2], SV.x)));     \
    SV.y = fmaf(P.y, KC[k0], fmaf(P.z, KC[k1], fmaf(P.w, KC[k2], SV.y)));     \
    SV.z = fmaf(P.z, KC[k0], fmaf(P.w, KC[k1], fmaf(nx,  KC[k2], SV.z)));     \
    SV.w = fmaf(P.w, KC[k0], fmaf(nx,  KC[k1], fmaf(ny,  KC[k2], SV.w)));

    // rolling right-halos for pred rows K, K+1 (SSA-renamed in the unroll)
    float ax = __shfl(p[0].x, l + 1, 64), ay = __shfl(p[0].y, l + 1, 64);
    float bx = __shfl(p[1].x, l + 1, 64), by = __shfl(p[1].y, l + 1, 64);
    float4 ghm2 = make_float4(0.f, 0.f, 0.f, 0.f);   // gh row g-2
    float4 ghm1 = make_float4(0.f, 0.f, 0.f, 0.f);   // gh row g-1
    float acc = 0.0f;

#pragma unroll
    for (int K = 0; K < 10; ++K) {
        const int g = o0 - 1 + K;   // GS/gh row index

        // late rhs loads: row o0+K+2 at K=2..5 (consumed at K+4)
        if (K >= 2 && K <= 5) {
            const int i = o0 + K + 2;
            if (i < o1) {
                const float* rr = rhsb + (size_t)i * OW + c0;
                r0[K + 2] = *(const float2*)rr;
                if (c0 + 2 < OW) r1[K + 2] = *(const float2*)(rr + 2);
            }
        }

        // halo for pred row K+2
        const float cx = __shfl(p[K + 2].x, l + 1, 64);
        const float cy = __shfl(p[K + 2].y, l + 1, 64);

        // GS row g: dual stencil + combine (guard is wave-uniform; false -> 0)
        float4 SL = make_float4(0.f, 0.f, 0.f, 0.f);
        float4 SD = make_float4(0.f, 0.f, 0.f, 0.f);
        if (g <= o1 && (unsigned)g < (unsigned)OH) {
            SROW(SL, p[K],     ax, ay, 0, 1, 2, kl)
            SROW(SL, p[K + 1], bx, by, 3, 4, 5, kl)
            SROW(SL, p[K + 2], cx, cy, 6, 7, 8, kl)
            SROW(SD, p[K],     ax, ay, 0, 1, 2, kd)
            SROW(SD, p[K + 1], bx, by, 3, 4, 5, kd)
            SROW(SD, p[K + 2], cx, cy, 6, 7, 8, kd)
        }
        float4 gs;
        gs.x = fmaf(s4.x, SL.x, sir4.x * SD.x);
        gs.y = fmaf(s4.y, SL.y, sir4.y * SD.y);
        gs.z = fmaf(s4.z, SL.z, sir4.z * SD.z);
        gs.w = fmaf(s4.w, SL.w, sir4.w * SD.w);

        // horizontal [1,2,1]
        const float up = __shfl(gs.w, l - 1, 64) * m0;  // lane0 reads lane63: 0
        const float dn = __shfl(gs.x, l + 1, 64);       // lane63: dead via m23
        float4 gh;
        gh.x = fmaf(2.f, gs.x, up   + gs.y);
        gh.y = fmaf(2.f, gs.y, gs.x + gs.z);
        gh.z = fmaf(2.f, gs.z, gs.y + gs.w);
        gh.w = fmaf(2.f, gs.w, gs.z + dn);

        // vertical [1,2,1]/16: emit output row i = g-1
        if (K >= 2) {
            const int i = g - 1;                        // = o0 + K - 2
            if (i < o1) {                               // uniform guard
                const float smx = (ghm2.x + 2.f * ghm1.x + gh.x) * 0.0625f;
                const float smy = (ghm2.y + 2.f * ghm1.y + gh.y) * 0.0625f;
                const float smz = (ghm2.z + 2.f * ghm1.z + gh.z) * 0.0625f;
                const float smw = (ghm2.w + 2.f * ghm1.w + gh.w) * 0.0625f;
                const float dx = smx - r0[K - 2].x;
                const float dy = smy - r0[K - 2].y;
                const float dz = (smz - r1[K - 2].x) * m23;
                const float dw = (smw - r1[K - 2].y) * m23;
                acc = fmaf(dx, dx, acc);
                acc = fmaf(dy, dy, acc);
                acc = fmaf(dz, dz, acc);
                acc = fmaf(dw, dw, acc);
            }
        }

        // SSA rolls (renamed away by the unroll)
        ghm2 = ghm1; ghm1 = gh;
        ax = bx; ay = by; bx = cx; by = cy;
    }
#undef SROW

    // wave reduce -> block partial -> ONE contention-free store per block
#pragma unroll
    for (int off = 32; off > 0; off >>= 1)
        acc += __shfl_down(acc, off, 64);
    __shared__ float wsum[4];
    if (l == 0) wsum[wv] = acc;
    __syncthreads();
    if (tid == 0)
        partials[blockIdx.x] = (wsum[0] + wsum[1]) + (wsum[2] + wsum[3]);
}

// Second stage: reduce N partials -> out (single block). Applies inv_n, so no
// memset dispatch is needed anywhere.
__global__ __launch_bounds__(256)
void reduce_kernel(const float* __restrict__ partials, float* __restrict__ out,
                   int n, float inv_n)
{
    const int tid = threadIdx.x;
    float a = 0.0f;
    for (int i = tid; i < n; i += 256) a += partials[i];
#pragma unroll
    for (int off = 32; off > 0; off >>= 1)
        a += __shfl_down(a, off, 64);
    __shared__ float w[4];
    if ((tid & 63) == 0) w[tid >> 6] = a;
    __syncthreads();
    if (tid == 0) out[0] = ((w[0] + w[1]) + (w[2] + w[3])) * inv_n;
}

extern "C" void kernel_launch(void* const* d_in, const int* in_sizes, int n_in,
                              void* d_out, int out_size, void* d_ws, size_t ws_size,
                              hipStream_t stream) {
    const float* pred = (const float*)d_in[0];
    const float* rhs  = (const float*)d_in[1];
    const float* KL   = (const float*)d_in[2];
    const float* KD   = (const float*)d_in[3];
    const float* RR   = (const float*)d_in[4];
    const float* ZZ   = (const float*)d_in[5];
    // d_in[6] = Gauss kernel [[1,2,1],[2,4,2],[1,2,1]]/16 — hardcoded, separable
    float* out = (float*)d_out;

    const int B = in_sizes[2] / 9;   // 256
    const int nblocks = B * 8;       // 256-thread blocks, 4 strips each
    const float inv_n = 1.0f / ((float)B * 254.0f * 254.0f);

    float* partials = (float*)d_ws;  // nblocks floats
    pde_loss_kernel<<<dim3(nblocks), dim3(256), 0, stream>>>(
        pred, rhs, KL, KD, RR, ZZ, partials);
    reduce_kernel<<<dim3(1), dim3(256), 0, stream>>>(partials, out, nblocks, inv_n);
}